// Round 4
// baseline (1630.352 us; speedup 1.0000x reference)
//
#include <hip/hip_runtime.h>
#include <math.h>

#define TT 8
#define NN 50000
#define EE 800000
#define FF 128
#define HH 128
// NHEADS=4, DH=32

// CSR bucketing
#define NB 98        // buckets per t: dst>>9
#define BSHIFT 9
#define CAP 14336    // bucket capacity (mean 8163, >60 sigma headroom for this input)
#define RS 16384     // region stride (uint2 entries)

typedef __attribute__((ext_vector_type(8))) short short8;
typedef __attribute__((ext_vector_type(4))) float f32x4;
typedef __attribute__((ext_vector_type(2))) float f32x2;
typedef unsigned char uchar;

__device__ inline unsigned bf16pack(float x) {
    unsigned u = __float_as_uint(x);
    return (u + 0x7fffu + ((u >> 16) & 1u)) >> 16;
}
// fp8->f32 values are exact in bf16 (3 mantissa bits subset of 7) -> truncate
__device__ inline unsigned pack2bf16_trunc(float lo, float hi) {
    return (__float_as_uint(hi) & 0xffff0000u) | (__float_as_uint(lo) >> 16);
}

// ---------------- casts ----------------

// fp32 -> fp8 e4m3 (4 elements / thread)
__global__ __launch_bounds__(256) void cast_x_kernel(const float4* __restrict__ in,
                                                     int* __restrict__ out, long n4) {
    long i = (long)blockIdx.x * 256 + threadIdx.x;
    if (i < n4) {
        float4 v = in[i];
        int w = __builtin_amdgcn_cvt_pk_fp8_f32(v.x, v.y, 0, false);
        w = __builtin_amdgcn_cvt_pk_fp8_f32(v.z, v.w, w, true);
        out[i] = w;
    }
}

// Bt[n][k] bf16, k in [0,256): rows 0..127 = Wl[k][n], 128..255 = Wr[k-128][n]
// batched over the 3 layers via blockIdx.y
__global__ __launch_bounds__(256) void wprep_kernel(const float* __restrict__ Wl1, const float* __restrict__ Wr1,
                                                    const float* __restrict__ Wl2, const float* __restrict__ Wr2,
                                                    const float* __restrict__ Wl3, const float* __restrict__ Wr3,
                                                    ushort* __restrict__ Bt1, ushort* __restrict__ Bt2,
                                                    ushort* __restrict__ Bt3) {
    int which = blockIdx.y;
    const float* Wl = (which == 0) ? Wl1 : (which == 1) ? Wl2 : Wl3;
    const float* Wr = (which == 0) ? Wr1 : (which == 1) ? Wr2 : Wr3;
    ushort* Bt = (which == 0) ? Bt1 : (which == 1) ? Bt2 : Bt3;
    int n = blockIdx.x;
    int k = threadIdx.x;
    float v = (k < 128) ? Wl[k * HH + n] : Wr[(k - 128) * HH + n];
    Bt[n * 256 + k] = (ushort)bf16pack(v);
}

// ---------------- bucketed CSR build ----------------

// Pass A: partition edges into (t, dst>>9) bucket regions. Per-bucket writes are
// sequential (block reserves a contiguous chunk) -> no random 4B line thrash.
__global__ __launch_bounds__(256) void partA_kernel(const int* __restrict__ ei,
                                                    int* __restrict__ bucketCursor,
                                                    uint2* __restrict__ pairs) {
    __shared__ int hist[NB];
    __shared__ int base[NB];
    int t = blockIdx.y, tid = threadIdx.x;
    const int* src = ei + (size_t)t * 2 * EE;
    const int* dst = src + EE;
    int e0 = blockIdx.x * 2048;
    int s[8], d[8];
#pragma unroll
    for (int k = 0; k < 8; k++) {
        int e = e0 + k * 256 + tid;
        bool ok = e < EE;
        s[k] = ok ? src[e] : -1;
        d[k] = ok ? dst[e] : -1;
    }
    if (tid < NB) hist[tid] = 0;
    __syncthreads();
#pragma unroll
    for (int k = 0; k < 8; k++)
        if (d[k] >= 0) atomicAdd(&hist[d[k] >> BSHIFT], 1);
    __syncthreads();
    if (tid < NB) {
        base[tid] = atomicAdd(&bucketCursor[t * NB + tid], hist[tid]);
        hist[tid] = 0;
    }
    __syncthreads();
#pragma unroll
    for (int k = 0; k < 8; k++)
        if (d[k] >= 0) {
            int b = d[k] >> BSHIFT;
            int idx = base[b] + atomicAdd(&hist[b], 1);
            if (idx < CAP)  // never taken for this input; keeps writes in-bounds generally
                pairs[((size_t)t * NB + b) * RS + idx] = make_uint2((unsigned)s[k], (unsigned)d[k]);
        }
}

// tiny per-t exclusive scan over bucket sizes
__global__ void bscan_kernel(const int* __restrict__ bucketCursor,
                             int* __restrict__ bucketBase) {
    int t = threadIdx.x;
    if (t < TT) {
        int run = 0;
        for (int b = 0; b < NB; b++) {
            bucketBase[t * NB + b] = run;
            int c = bucketCursor[t * NB + b];
            run += (c > CAP ? CAP : c);
        }
    }
}

// Pass B: one block per bucket. Local histogram + scan + scatter fully in LDS,
// then coalesced streams of cnt / rowstart / srcs_sorted.
__global__ __launch_bounds__(256) void partB_kernel(const uint2* __restrict__ pairs,
                                                    const int* __restrict__ bucketCursor,
                                                    const int* __restrict__ bucketBase,
                                                    int* __restrict__ cnt,
                                                    int* __restrict__ rowstart,
                                                    int* __restrict__ srcs_sorted) {
    __shared__ int hist[512];
    __shared__ int offs[512];
    __shared__ int sh2[256];
    __shared__ int staged[CAP];
    int t = blockIdx.y, b = blockIdx.x, tid = threadIdx.x;
    int n0 = b << BSHIFT;
    int nn = NN - n0; if (nn > 512) nn = 512;
    int cb = bucketCursor[t * NB + b]; if (cb > CAP) cb = CAP;
    int ebase = bucketBase[t * NB + b];
    const uint2* P = pairs + ((size_t)t * NB + b) * RS;

    hist[tid] = 0; hist[tid + 256] = 0;
    __syncthreads();
    for (int i = tid; i < cb; i += 256) atomicAdd(&hist[(int)P[i].y - n0], 1);
    __syncthreads();
    int a0 = hist[2 * tid], a1 = hist[2 * tid + 1];
    sh2[tid] = a0 + a1;
    __syncthreads();
    for (int off = 1; off < 256; off <<= 1) {
        int v = (tid >= off) ? sh2[tid - off] : 0;
        __syncthreads();
        sh2[tid] += v;
        __syncthreads();
    }
    int excl = sh2[tid] - (a0 + a1);
    offs[2 * tid] = excl;
    offs[2 * tid + 1] = excl + a0;
    __syncthreads();
    for (int i = tid; i < nn; i += 256) {
        cnt[(size_t)t * NN + n0 + i] = hist[i];
        rowstart[(size_t)t * NN + n0 + i] = ebase + offs[i];
    }
    __syncthreads();
    hist[tid] = offs[tid]; hist[tid + 256] = offs[tid + 256];  // reuse as cursors
    __syncthreads();
    for (int i = tid; i < cb; i += 256) {
        uint2 p = P[i];
        int slot = atomicAdd(&hist[(int)p.y - n0], 1);
        staged[slot] = (int)p.x;
    }
    __syncthreads();
    int* outp = srcs_sorted + (size_t)t * EE + ebase;
    for (int i = tid; i < cb; i += 256) outp[i] = staged[i];
}

// ---------------- fused neighbor-mean + dual GEMM + bias + relu ----------------
// Per block: 128 output rows. Phase A: the block's 4 waves compute the neighbor
// mean for their own 32 nodes each (fp8 gather, f32 accumulate -- same proven
// loop as the standalone agg kernel) and write bf16 rows into aggbuf in LDS.
// Phase B: 4-stage MFMA loop. Stages 0-1 read A-frags from aggbuf (ds_read);
// stages 2-3 read raw fp8 features per-fragment from global and convert in
// registers (no As buffer). B-frags read directly from the 64 KB L2-hot Bt
// (no Bs buffer, no per-stage barriers). Deletes aggq write+read (102 MB/layer)
// and 1 launch/layer; agg VALU work overlaps MFMA across resident blocks.
// aggbuf row stride 136 shorts: 16B-aligned rows, bank-balanced b128 reads.
// POOL=1 (layer 3): skip fp8 store, mean-pool f32 relu output into `pooled`.
template <int POOL>
__global__ __launch_bounds__(256) void fused_agg_gemm_kernel(
        const uchar* __restrict__ xinF,
        const int* __restrict__ srcs_sortedF,
        const int* __restrict__ rowstartF,
        const int* __restrict__ cntF,
        const ushort* __restrict__ Bt,
        const float* __restrict__ bias,
        uchar* __restrict__ outF,
        float* __restrict__ pooled) {
    __shared__ ushort aggbuf[128 * 136];   // 34816 B; reused as Cs / colsum in epilogue

    int t = blockIdx.y;
    const char* xb = (const char*)xinF + (size_t)t * NN * HH;
    const int* srcs = srcs_sortedF + (size_t)t * EE;
    const int* rsA = rowstartF + t * NN;
    const int* cnA = cntF + t * NN;
    uchar* out = outF + (size_t)t * NN * HH;

    int tid = threadIdx.x;
    int row0 = blockIdx.x * 128;
    int lane = tid & 63, wave = tid >> 6;
    int l15 = lane & 15, quad = lane >> 4;
    unsigned lby = (unsigned)(l15 << 3);   // byte offset within a 128B fp8 row

    // ---- Phase A: aggregation into aggbuf (wave w -> rows w*32 .. w*32+31)
    for (int it = 0; it < 32; ++it) {
        int rloc = wave * 32 + it;
        int node = row0 + rloc;
        f32x2 A0 = (f32x2){0.f, 0.f}, A1 = A0, A2 = A0, A3 = A0;
        int c = 0;
        if (node < NN) {
            int rs = rsA[node];
            c = cnA[node];
            int j = quad;
            for (; j + 12 < c; j += 16) {
                int i0 = srcs[rs + j];
                int i1 = srcs[rs + j + 4];
                int i2 = srcs[rs + j + 8];
                int i3 = srcs[rs + j + 12];
                uint2 v0 = *(const uint2*)(xb + (((unsigned)i0 << 7) | lby));
                uint2 v1 = *(const uint2*)(xb + (((unsigned)i1 << 7) | lby));
                uint2 v2 = *(const uint2*)(xb + (((unsigned)i2 << 7) | lby));
                uint2 v3 = *(const uint2*)(xb + (((unsigned)i3 << 7) | lby));
                A0 += __builtin_amdgcn_cvt_pk_f32_fp8((int)v0.x, false);
                A1 += __builtin_amdgcn_cvt_pk_f32_fp8((int)v0.x, true);
                A2 += __builtin_amdgcn_cvt_pk_f32_fp8((int)v0.y, false);
                A3 += __builtin_amdgcn_cvt_pk_f32_fp8((int)v0.y, true);
                A0 += __builtin_amdgcn_cvt_pk_f32_fp8((int)v1.x, false);
                A1 += __builtin_amdgcn_cvt_pk_f32_fp8((int)v1.x, true);
                A2 += __builtin_amdgcn_cvt_pk_f32_fp8((int)v1.y, false);
                A3 += __builtin_amdgcn_cvt_pk_f32_fp8((int)v1.y, true);
                A0 += __builtin_amdgcn_cvt_pk_f32_fp8((int)v2.x, false);
                A1 += __builtin_amdgcn_cvt_pk_f32_fp8((int)v2.x, true);
                A2 += __builtin_amdgcn_cvt_pk_f32_fp8((int)v2.y, false);
                A3 += __builtin_amdgcn_cvt_pk_f32_fp8((int)v2.y, true);
                A0 += __builtin_amdgcn_cvt_pk_f32_fp8((int)v3.x, false);
                A1 += __builtin_amdgcn_cvt_pk_f32_fp8((int)v3.x, true);
                A2 += __builtin_amdgcn_cvt_pk_f32_fp8((int)v3.y, false);
                A3 += __builtin_amdgcn_cvt_pk_f32_fp8((int)v3.y, true);
            }
            if (j + 4 < c) {
                int i0 = srcs[rs + j];
                int i1 = srcs[rs + j + 4];
                uint2 v0 = *(const uint2*)(xb + (((unsigned)i0 << 7) | lby));
                uint2 v1 = *(const uint2*)(xb + (((unsigned)i1 << 7) | lby));
                A0 += __builtin_amdgcn_cvt_pk_f32_fp8((int)v0.x, false);
                A1 += __builtin_amdgcn_cvt_pk_f32_fp8((int)v0.x, true);
                A2 += __builtin_amdgcn_cvt_pk_f32_fp8((int)v0.y, false);
                A3 += __builtin_amdgcn_cvt_pk_f32_fp8((int)v0.y, true);
                A0 += __builtin_amdgcn_cvt_pk_f32_fp8((int)v1.x, false);
                A1 += __builtin_amdgcn_cvt_pk_f32_fp8((int)v1.x, true);
                A2 += __builtin_amdgcn_cvt_pk_f32_fp8((int)v1.y, false);
                A3 += __builtin_amdgcn_cvt_pk_f32_fp8((int)v1.y, true);
                j += 8;
            }
            if (j < c) {
                int i0 = srcs[rs + j];
                uint2 v0 = *(const uint2*)(xb + (((unsigned)i0 << 7) | lby));
                A0 += __builtin_amdgcn_cvt_pk_f32_fp8((int)v0.x, false);
                A1 += __builtin_amdgcn_cvt_pk_f32_fp8((int)v0.x, true);
                A2 += __builtin_amdgcn_cvt_pk_f32_fp8((int)v0.y, false);
                A3 += __builtin_amdgcn_cvt_pk_f32_fp8((int)v0.y, true);
            }
        }
#pragma unroll
        for (int o = 16; o <= 32; o <<= 1) {
            f32x2 B0, B1, B2, B3;
            B0.x = __shfl_xor(A0.x, o, 64); B0.y = __shfl_xor(A0.y, o, 64);
            B1.x = __shfl_xor(A1.x, o, 64); B1.y = __shfl_xor(A1.y, o, 64);
            B2.x = __shfl_xor(A2.x, o, 64); B2.y = __shfl_xor(A2.y, o, 64);
            B3.x = __shfl_xor(A3.x, o, 64); B3.y = __shfl_xor(A3.y, o, 64);
            A0 += B0; A1 += B1; A2 += B2; A3 += B3;
        }
        if (quad == 0) {
            float inv = 1.0f / (float)(c > 0 ? c : 1);
            uint4 w;
            w.x = bf16pack(A0.x * inv) | (bf16pack(A0.y * inv) << 16);
            w.y = bf16pack(A1.x * inv) | (bf16pack(A1.y * inv) << 16);
            w.z = bf16pack(A2.x * inv) | (bf16pack(A2.y * inv) << 16);
            w.w = bf16pack(A3.x * inv) | (bf16pack(A3.y * inv) << 16);
            *(uint4*)&aggbuf[rloc * 136 + l15 * 8] = w;
        }
    }
    __syncthreads();

    // ---- Phase B: MFMA stages
    int wm = wave >> 1, wn = wave & 1;
    f32x4 acc[4][4];
#pragma unroll
    for (int i = 0; i < 4; i++)
#pragma unroll
        for (int j = 0; j < 4; j++) acc[i][j] = (f32x4){0.f, 0.f, 0.f, 0.f};

    union frag_u { short8 s8; uint4 u4; };

#pragma unroll
    for (int s = 0; s < 4; s++) {
#pragma unroll
        for (int ks = 0; ks < 2; ks++) {
            int kq = ks * 32 + quad * 8;       // k within the 64-wide stage slice
            short8 a[4], b[4];
            if (s < 2) {
                int kg = s * 64 + kq;          // agg cols 0..127
#pragma unroll
                for (int i = 0; i < 4; i++)
                    a[i] = *(const short8*)&aggbuf[(wm * 64 + i * 16 + l15) * 136 + kg];
            } else {
                int kg = (s - 2) * 64 + kq;    // raw-x cols 0..127
#pragma unroll
                for (int i = 0; i < 4; i++) {
                    int r = row0 + wm * 64 + i * 16 + l15;
                    uint2 v = make_uint2(0u, 0u);
                    if (r < NN) v = *(const uint2*)(xb + (((unsigned)r << 7) + (unsigned)kg));
                    f32x2 lo0 = __builtin_amdgcn_cvt_pk_f32_fp8((int)v.x, false);
                    f32x2 hi0 = __builtin_amdgcn_cvt_pk_f32_fp8((int)v.x, true);
                    f32x2 lo1 = __builtin_amdgcn_cvt_pk_f32_fp8((int)v.y, false);
                    f32x2 hi1 = __builtin_amdgcn_cvt_pk_f32_fp8((int)v.y, true);
                    frag_u fu;
                    fu.u4 = make_uint4(pack2bf16_trunc(lo0.x, lo0.y),
                                       pack2bf16_trunc(hi0.x, hi0.y),
                                       pack2bf16_trunc(lo1.x, lo1.y),
                                       pack2bf16_trunc(hi1.x, hi1.y));
                    a[i] = fu.s8;
                }
            }
            int kb = s * 64 + kq;              // k within Bt's 256-wide layout
#pragma unroll
            for (int j = 0; j < 4; j++)
                b[j] = *(const short8*)&Bt[(wn * 64 + j * 16 + l15) * 256 + kb];
#pragma unroll
            for (int i = 0; i < 4; i++)
#pragma unroll
                for (int j = 0; j < 4; j++)
                    acc[i][j] = __builtin_amdgcn_mfma_f32_16x16x32_bf16(a[i], b[j], acc[i][j], 0, 0, 0);
        }
    }
    __syncthreads();   // all aggbuf reads done; safe to reuse LDS for the epilogue

    if (POOL == 0) {
        // epilogue: bias + relu + fp8 pack into LDS, then coalesced stores
        uchar* Cs = (uchar*)aggbuf;
#pragma unroll
        for (int i = 0; i < 4; i++)
#pragma unroll
            for (int j = 0; j < 4; j++) {
                int col = wn * 64 + j * 16 + l15;
                float bb = bias[col];
#pragma unroll
                for (int r = 0; r < 4; r++) {
                    int rl = wm * 64 + i * 16 + quad * 4 + r;
                    float v = fmaxf(acc[i][j][r] + bb, 0.f);
                    int pk = __builtin_amdgcn_cvt_pk_fp8_f32(v, 0.f, 0, false);
                    Cs[rl * 144 + col] = (uchar)(pk & 0xff);
                }
            }
        __syncthreads();

        int orow = tid >> 1;
        int ocb = (tid & 1) * 64;
        if (row0 + orow < NN) {
#pragma unroll
            for (int c = 0; c < 4; c++)
                *(uint4*)&out[(size_t)(row0 + orow) * HH + ocb + c * 16] =
                    *(const uint4*)&Cs[orow * 144 + ocb + c * 16];
        }
    } else {
        // fused mean-pool epilogue: per-block column sums -> one atomicAdd/column
        float* colsum = (float*)aggbuf;
        if (tid < HH) colsum[tid] = 0.f;
        __syncthreads();
#pragma unroll
        for (int j = 0; j < 4; j++) {
            int col = wn * 64 + j * 16 + l15;
            float bb = bias[col];
            float ps = 0.f;
#pragma unroll
            for (int i = 0; i < 4; i++)
#pragma unroll
                for (int r = 0; r < 4; r++) {
                    int rl = wm * 64 + i * 16 + quad * 4 + r;
                    float v = fmaxf(acc[i][j][r] + bb, 0.f);
                    ps += (row0 + rl < NN) ? v : 0.f;
                }
            ps += __shfl_xor(ps, 16, 64);
            ps += __shfl_xor(ps, 32, 64);
            if (quad == 0) atomicAdd(&colsum[col], ps);
        }
        __syncthreads();
        if (tid < HH)
            atomicAdd(&pooled[blockIdx.y * HH + tid], colsum[tid] * (1.0f / (float)NN));
    }
}

// ---------------- attention + MLP head (tiny, fp32) ----------------
__global__ __launch_bounds__(256) void head_kernel(const float* __restrict__ pooled,
                                                   const float* __restrict__ Wq, const float* __restrict__ bq,
                                                   const float* __restrict__ Wk, const float* __restrict__ bk,
                                                   const float* __restrict__ Wv, const float* __restrict__ bv,
                                                   const float* __restrict__ Wo, const float* __restrict__ bo,
                                                   const float* __restrict__ Wh1, const float* __restrict__ bh1,
                                                   const float* __restrict__ Wh2, const float* __restrict__ bh2,
                                                   float* __restrict__ out) {
    __shared__ float seq[TT * HH];
    __shared__ float kb[TT * HH];
    __shared__ float vbuf[TT * HH];
    __shared__ float q7[HH];
    __shared__ float sc[4][8];
    __shared__ float zb[HH];
    __shared__ float ob[HH];
    __shared__ float h1b[64];
    int tid = threadIdx.x;
    for (int i = tid; i < TT * HH; i += 256) seq[i] = pooled[i];
    __syncthreads();
    for (int i = tid; i < TT * HH; i += 256) {
        int t = i >> 7, h = i & 127;
        float sk = bk[h], sv = bv[h];
        for (int j = 0; j < HH; j++) {
            float s = seq[t * HH + j];
            sk += s * Wk[j * HH + h];
            sv += s * Wv[j * HH + h];
        }
        kb[i] = sk;
        vbuf[i] = sv;
    }
    if (tid < HH) {
        float sq = bq[tid];
        for (int j = 0; j < HH; j++) sq += seq[7 * HH + j] * Wq[j * HH + tid];
        q7[tid] = sq;
    }
    __syncthreads();
    if (tid < 32) {
        int g = tid >> 3, tt = tid & 7;
        float s = 0.f;
        for (int d = 0; d < 32; d++) s += q7[g * 32 + d] * kb[tt * HH + g * 32 + d];
        sc[g][tt] = s * 0.1767766952966369f;
    }
    __syncthreads();
    if (tid < 4) {
        float m = -1e30f;
        for (int i = 0; i < 8; i++) m = fmaxf(m, sc[tid][i]);
        float e[8], sum = 0.f;
        for (int i = 0; i < 8; i++) { e[i] = expf(sc[tid][i] - m); sum += e[i]; }
        for (int i = 0; i < 8; i++) sc[tid][i] = e[i] / sum;
    }
    __syncthreads();
    if (tid < HH) {
        int g = tid >> 5;
        float s = 0.f;
        for (int t = 0; t < 8; t++) s += sc[g][t] * vbuf[t * HH + tid];
        zb[tid] = s;
    }
    __syncthreads();
    if (tid < HH) {
        float s = bo[tid];
        for (int j = 0; j < HH; j++) s += zb[j] * Wo[j * HH + tid];
        ob[tid] = s;
    }
    __syncthreads();
    if (tid < 64) {
        float s = bh1[tid];
        for (int j = 0; j < HH; j++) s += ob[j] * Wh1[j * 64 + tid];
        h1b[tid] = fmaxf(s, 0.f);
    }
    __syncthreads();
    if (tid == 0) {
        float s = bh2[0];
        for (int j = 0; j < 64; j++) s += h1b[j] * Wh2[j];
        out[0] = 1.0f / (1.0f + expf(-s));
    }
}

// ---------------- launch ----------------

extern "C" void kernel_launch(void* const* d_in, const int* in_sizes, int n_in,
                              void* d_out, int out_size, void* d_ws, size_t ws_size,
                              hipStream_t stream) {
    const float* xs = (const float*)d_in[0];
    const int* ei = (const int*)d_in[1];
    const float* Wl1 = (const float*)d_in[2];
    const float* Wr1 = (const float*)d_in[3];
    const float* b1 = (const float*)d_in[4];
    const float* Wl2 = (const float*)d_in[5];
    const float* Wr2 = (const float*)d_in[6];
    const float* b2 = (const float*)d_in[7];
    const float* Wl3 = (const float*)d_in[8];
    const float* Wr3 = (const float*)d_in[9];
    const float* b3 = (const float*)d_in[10];
    const float* Wq = (const float*)d_in[11];
    const float* bq = (const float*)d_in[12];
    const float* Wk = (const float*)d_in[13];
    const float* bk = (const float*)d_in[14];
    const float* Wv = (const float*)d_in[15];
    const float* bv = (const float*)d_in[16];
    const float* Wo = (const float*)d_in[17];
    const float* bo = (const float*)d_in[18];
    const float* Wh1 = (const float*)d_in[19];
    const float* bh1 = (const float*)d_in[20];
    const float* Wh2 = (const float*)d_in[21];
    const float* bh2 = (const float*)d_in[22];

    size_t off = 0;
    char* base = (char*)d_ws;
    auto carve = [&](size_t bytes) -> char* {
        char* p = base + off;
        off += (bytes + 255) & ~(size_t)255;
        return p;
    };
    int* cnt = (int*)carve((size_t)TT * NN * 4);
    int* rowstart = (int*)carve((size_t)TT * NN * 4);
    int* srcs_sorted = (int*)carve((size_t)TT * EE * 4);
    int* bucketCursor = (int*)carve((size_t)TT * NB * 4);
    int* bucketBase = (int*)carve((size_t)TT * NB * 4);
    uint2* pairs = (uint2*)carve((size_t)TT * NB * RS * 8);
    uchar* xq = (uchar*)carve((size_t)TT * NN * HH);
    uchar* h1q = (uchar*)carve((size_t)TT * NN * HH);
    uchar* h2q = (uchar*)carve((size_t)TT * NN * HH);
    ushort* Bt1 = (ushort*)carve((size_t)128 * 256 * 2);
    ushort* Bt2 = (ushort*)carve((size_t)128 * 256 * 2);
    ushort* Bt3 = (ushort*)carve((size_t)128 * 256 * 2);
    float* pooled = (float*)carve((size_t)TT * HH * 4);

    hipMemsetAsync(pooled, 0, (size_t)TT * HH * 4, stream);
    hipMemsetAsync(bucketCursor, 0, (size_t)TT * NB * 4, stream);

    long n4 = (long)TT * NN * FF / 4;
    cast_x_kernel<<<(int)((n4 + 255) / 256), 256, 0, stream>>>((const float4*)xs, (int*)xq, n4);
    wprep_kernel<<<dim3(128, 3), 256, 0, stream>>>(Wl1, Wr1, Wl2, Wr2, Wl3, Wr3, Bt1, Bt2, Bt3);

    // bucketed CSR
    partA_kernel<<<dim3((EE + 2047) / 2048, TT), 256, 0, stream>>>(ei, bucketCursor, pairs);
    bscan_kernel<<<1, 64, 0, stream>>>(bucketCursor, bucketBase);
    partB_kernel<<<dim3(NB, TT), 256, 0, stream>>>(pairs, bucketCursor, bucketBase,
                                                   cnt, rowstart, srcs_sorted);

    const int gemmGrid = (NN + 127) / 128;  // 391

    // layer 1
    fused_agg_gemm_kernel<0><<<dim3(gemmGrid, TT), 256, 0, stream>>>(
        xq, srcs_sorted, rowstart, cnt, Bt1, b1, h1q, nullptr);
    // layer 2
    fused_agg_gemm_kernel<0><<<dim3(gemmGrid, TT), 256, 0, stream>>>(
        h1q, srcs_sorted, rowstart, cnt, Bt2, b2, h2q, nullptr);
    // layer 3: mean-pool fused into the epilogue
    fused_agg_gemm_kernel<1><<<dim3(gemmGrid, TT), 256, 0, stream>>>(
        h2q, srcs_sorted, rowstart, cnt, Bt3, b3, h1q, pooled);

    head_kernel<<<1, 256, 0, stream>>>(pooled, Wq, bq, Wk, bk, Wv, bv, Wo, bo,
                                       Wh1, bh1, Wh2, bh2, (float*)d_out);
}